// Round 5
// baseline (263.513 us; speedup 1.0000x reference)
//
#include <hip/hip_runtime.h>
#include <cstddef>

#define BATCH 4
#define CH    16
#define HH    512
#define WW    512
#define HID   128
#define K3    48      // 3*CH
#define YSTR  68      // sY row stride bf16: 64 feat slots + 4 pad; byte stride 136
                      //   -> b64 writes 8B-aligned, bank stride 34 (perfect-tile windows)
#define HSTR  136     // sH row stride (128 + 8 bank-pad), 272 B
#define XSTR  20      // sXC row stride fp32: b128-aligned (80 B), well-spread banks

typedef __bf16 bf16x8 __attribute__((ext_vector_type(8)));
typedef __bf16 bf16x4 __attribute__((ext_vector_type(4)));
typedef float  f32x4  __attribute__((ext_vector_type(4)));

static __device__ __forceinline__ f32x4 mfma16(bf16x8 a, bf16x8 b, f32x4 c) {
    return __builtin_amdgcn_mfma_f32_16x16x32_bf16(a, b, c, 0, 0, 0);
}

// One block per (b, image row); 8 segments of 64 px.
// v8 = v4's proven 100us structure (LA/LB ping-pong, acc[8] batched MFMA,
// compiler-scheduled issue_loads(s+2) post-#B) + three audited changes:
//  1) packed sY writes (3x ds_write_b64) + packed sXC (1x b128) instead of
//     16 scalar writes: kills the 8-way-conflict source (4.98M cycles, bank
//     = 4*px mod 32 at old YSTR=72) and ~12 LDS instr/wave-seg.
//  2) a0r[8] W0-frags pinned in 32 VGPRs via empty asm "+v" (result of
//     volatile asm is un-rematerializable -> RA cannot re-sink the loads;
//     v6's plain hoist spilled, v7's was silently dropped at VGPR=76).
//     a1r/aw stay in LDS: peak live ~ 84(v4) + 32 + temps ~ 130 < 168 cap.
//  3) XCD row swizzle kept (FETCH 113.7 -> ~36 MB, halo L2 reuse).
// NOT repeated: per-t accumulator (v7: serialized MFMA chains, MfmaUtil
// 8.5->6.2), sched_barrier load pin (v5: m141-style regression).
__global__ __launch_bounds__(256, 3)
void ca_mfma8(const float* __restrict__ x, const float* __restrict__ w0,
              const float* __restrict__ b0, const float* __restrict__ w1,
              const float* __restrict__ ru, float* __restrict__ out)
{
    // frag-ordered weights: sW0[ks][t][lane][8], sW1[s][lane][8]
    __shared__ __align__(16) __bf16 sW0[2 * 8 * 64 * 8];   // 16 KB
    __shared__ __align__(16) __bf16 sW1[4 * 64 * 8];       //  4 KB
    __shared__ __align__(16) __bf16 sY[64 * YSTR];         // 8.5 KB
    __shared__ __align__(16) __bf16 sH[64 * HSTR];         // 17.0 KB
    __shared__ __align__(16) float sXC[64 * XSTR];         // 5.0 KB
    __shared__ float sRU[WW];                              // 2.0 KB (53760 B total, 3 blk/CU)

    const int tid  = threadIdx.x;
    const int lane = tid & 63;
    const int wv   = tid >> 6;
    const int p    = lane & 15;   // MFMA m/n index
    const int q    = lane >> 4;   // quad

    // bijective XCD swizzle: XCD k owns rows [256k, 256k+256) -> halo rows
    // land in the same XCD's L2
    const int orig = blockIdx.x;
    const int row  = ((orig & 7) << 8) | (orig >> 3);
    const int b    = row >> 9;
    const int i    = row & (HH - 1);

    const size_t plane = (size_t)HH * WW;
    const float* xb    = x + (size_t)b * CH * plane + (size_t)i * WW;
    const bool   up    = (i > 0), dn = (i < HH - 1);
    const int    px    = tid & 63;        // feature-build pixel

    // stencil load buffers (depth-2 ping-pong): [ch 0..3][ul,u,ur, l,m,r, dl,d,dr]
    float LA[4][9], LB[4][9];

    auto issue_loads = [&](int s, float (&L)[4][9]) {
        const int j  = s * 64 + px;
        const bool lf = (j > 0), rt = (j < WW - 1);
        #pragma unroll
        for (int k = 0; k < 4; ++k) {
            const float* c0 = xb + (size_t)(4 * wv + k) * plane + j;
            L[k][0] = (up && lf) ? c0[-WW - 1] : 0.f;
            L[k][1] =  up        ? c0[-WW]     : 0.f;
            L[k][2] = (up && rt) ? c0[-WW + 1] : 0.f;
            L[k][3] =  lf        ? c0[-1]      : 0.f;
            L[k][4] =              c0[0];
            L[k][5] =  rt        ? c0[1]       : 0.f;
            L[k][6] = (dn && lf) ? c0[WW - 1]  : 0.f;
            L[k][7] =  dn        ? c0[WW]      : 0.f;
            L[k][8] = (dn && rt) ? c0[WW + 1]  : 0.f;
        }
    };

    // issue segment-0/1 stencil loads first: they complete under the weight
    // staging + barrier below (free prologue latency hiding)
    issue_loads(0, LA);
    issue_loads(1, LB);

    // ---- stage W0 (+bias at k==48) into LDS, frag-ordered ----
    for (int e = tid; e < 1024; e += 256) {
        const int ks = e >> 9, rem = e & 511;
        const int t = rem >> 6, ln = rem & 63;
        const int pp = ln & 15, qq = ln >> 4;
        const int o = 16 * t + pp;
        bf16x8 v;
        #pragma unroll
        for (int j = 0; j < 8; ++j) {
            const int k = 32 * ks + 8 * qq + j;
            float val;
            if (k < K3)       val = w0[o * K3 + k];
            else if (k == K3) val = b0[o];
            else              val = 0.f;
            v[j] = (__bf16)val;
        }
        *(bf16x8*)&sW0[e * 8] = v;
    }
    // ---- stage W1 [16 x 128] frag-ordered: one entry per thread ----
    {
        const int e = tid;                 // 256 entries total
        const int s = e >> 6, ln = e & 63;
        const int pp = ln & 15, qq = ln >> 4;
        bf16x8 v;
        #pragma unroll
        for (int j = 0; j < 8; ++j)
            v[j] = (__bf16)w1[pp * HID + 32 * s + 8 * qq + j];
        *(bf16x8*)&sW1[e * 8] = v;
    }
    // ---- stage the mask row (512 floats): epilogue reads LDS, not HBM ----
    for (int e = tid; e < WW; e += 256)
        sRU[e] = ru[(size_t)b * plane + (size_t)i * WW + e];
    // ---- static K-pad of sY: feature 48 = 1.0 (bias), 49..63 = 0 ----
    if (tid < 64) {
        bf16x4 zb = {(__bf16)1.0f, (__bf16)0.f, (__bf16)0.f, (__bf16)0.f};
        bf16x4 zz = {(__bf16)0.f, (__bf16)0.f, (__bf16)0.f, (__bf16)0.f};
        *(bf16x4*)&sY[tid * YSTR + 48] = zb;
        *(bf16x4*)&sY[tid * YSTR + 52] = zz;
        *(bf16x4*)&sY[tid * YSTR + 56] = zz;
        *(bf16x4*)&sY[tid * YSTR + 60] = zz;
    }
    asm volatile("s_waitcnt lgkmcnt(0)");
    __builtin_amdgcn_s_barrier();

    // ---- pin the ks=0 half of W0 frags in 32 VGPRs. The empty volatile asm
    // makes the value opaque (not re-loadable from LDS), so the RA must keep
    // it live across the loop. a1r (ks=1) + aw deliberately left in LDS to
    // bound peak pressure. ----
    bf16x8 a0r[8];
    #pragma unroll
    for (int t = 0; t < 8; ++t) {
        a0r[t] = *(const bf16x8*)&sW0[((0 * 8 + t) * 64 + lane) * 8];
        asm volatile("" : "+v"(a0r[t]));
    }

    auto seg_body = [&](int s, float (&L)[4][9]) {
        // ---- compute Sobel features from in-flight loads (VALU only) ----
        float fm[4], fgx[4], fgy[4];
        #pragma unroll
        for (int k = 0; k < 4; ++k) {
            fm[k]  = L[k][4];
            fgx[k] = (L[k][2] - L[k][0]) + 2.f * (L[k][5] - L[k][3]) + (L[k][8] - L[k][6]);
            fgy[k] = (L[k][6] - L[k][0]) + 2.f * (L[k][7] - L[k][1]) + (L[k][8] - L[k][2]);
        }
        // #A: all waves done reading sY/sXC of segment s-1
        __builtin_amdgcn_s_barrier();
        // packed feature writes: 3x b64 + 1x b128 (was 16 scalar; 8-way
        // bank conflicts at old stride eliminated)
        {
            bf16x4 vm = {(__bf16)fm[0],  (__bf16)fm[1],  (__bf16)fm[2],  (__bf16)fm[3]};
            bf16x4 vx = {(__bf16)fgx[0], (__bf16)fgx[1], (__bf16)fgx[2], (__bf16)fgx[3]};
            bf16x4 vy = {(__bf16)fgy[0], (__bf16)fgy[1], (__bf16)fgy[2], (__bf16)fgy[3]};
            *(bf16x4*)&sY[px * YSTR + 4 * wv]          = vm;
            *(bf16x4*)&sY[px * YSTR + CH + 4 * wv]     = vx;
            *(bf16x4*)&sY[px * YSTR + 2 * CH + 4 * wv] = vy;
            f32x4 vc = {fm[0], fm[1], fm[2], fm[3]};
            *(f32x4*)&sXC[px * XSTR + 4 * wv] = vc;
        }
        // #B: LDS writes visible; no vmcnt drain -> prefetched stencil loads
        // and output stores stay in flight across the barrier
        asm volatile("s_waitcnt lgkmcnt(0)");
        __builtin_amdgcn_s_barrier();

        // next-next segment's stencil loads (compiler-scheduled placement)
        if (s < 6) issue_loads(s + 2, L);

        // ---- MFMA phase: wave wv owns pixels 16*wv .. 16*wv+15 ----
        const int pxg = 16 * wv + p;
        const bf16x8 yb0 = *(const bf16x8*)&sY[pxg * YSTR + 8 * q];
        const bf16x8 yb1 = *(const bf16x8*)&sY[pxg * YSTR + 32 + 8 * q];

        f32x4 acc[8];
        #pragma unroll
        for (int t = 0; t < 8; ++t) {
            const bf16x8 a1 = *(const bf16x8*)&sW0[((1 * 8 + t) * 64 + lane) * 8];
            acc[t] = f32x4{0.f, 0.f, 0.f, 0.f};
            acc[t] = mfma16(a0r[t], yb0, acc[t]);
            acc[t] = mfma16(a1,     yb1, acc[t]);
        }
        // relu + cvt -> sH[pxg][o], o = 16t + 4q + r (D-layout: col=px, row=4q+r)
        #pragma unroll
        for (int t = 0; t < 8; ++t) {
            bf16x4 hv;
            #pragma unroll
            for (int r = 0; r < 4; ++r)
                hv[r] = (__bf16)fmaxf(acc[t][r], 0.f);
            *(bf16x4*)&sH[pxg * HSTR + 16 * t + 4 * q] = hv;
        }
        // same-wave LDS write->read, wave-private rows: no barrier needed
        f32x4 u = f32x4{0.f, 0.f, 0.f, 0.f};
        #pragma unroll
        for (int ss = 0; ss < 4; ++ss) {
            const bf16x8 hb = *(const bf16x8*)&sH[pxg * HSTR + 32 * ss + 8 * q];
            const bf16x8 aw = *(const bf16x8*)&sW1[(ss * 64 + lane) * 8];
            u = mfma16(aw, hb, u);
        }

        // ---- epilogue: out[c][jg] = xc + u[r]*mask, c = 4q + r ----
        const int jg = s * 64 + pxg;
        const float rv = sRU[jg];          // LDS, not HBM
        const float m  = (rv > 0.5f) ? 1.f : 0.f;
        const f32x4 xc = *(const f32x4*)&sXC[pxg * XSTR + 4 * q];
        float* ob = out + (size_t)b * CH * plane + (size_t)i * WW + jg;
        #pragma unroll
        for (int r = 0; r < 4; ++r) {
            const int c = 4 * q + r;
            ob[(size_t)c * plane] = fmaf(u[r], m, xc[r]);
        }
    };

    for (int sp = 0; sp < 4; ++sp) {
        seg_body(2 * sp,     LA);
        seg_body(2 * sp + 1, LB);
    }
}

extern "C" void kernel_launch(void* const* d_in, const int* in_sizes, int n_in,
                              void* d_out, int out_size, void* d_ws, size_t ws_size,
                              hipStream_t stream) {
    const float* x  = (const float*)d_in[0];
    const float* w0 = (const float*)d_in[1];
    const float* b0 = (const float*)d_in[2];
    const float* w1 = (const float*)d_in[3];
    const float* ru = (const float*)d_in[4];
    float* out = (float*)d_out;

    dim3 grid(BATCH * HH);   // 2048 blocks: one per (batch, image row)
    dim3 block(256);
    hipLaunchKernelGGL(ca_mfma8, grid, block, 0, stream, x, w0, b0, w1, ru, out);
}

// Round 6
// 192.575 us; speedup vs baseline: 1.3684x; 1.3684x over previous
//
#include <hip/hip_runtime.h>
#include <cstddef>

#define BATCH 4
#define CH    16
#define HH    512
#define WW    512
#define HID   128
#define K3    48      // 3*CH
#define YSTR  72      // sY row stride bf16 (64 feat slots + 8 pad); 144 B, b128-aligned reads
#define HSTR  136     // sH row stride (128 + 8 bank-pad), 272 B

typedef __bf16 bf16x8 __attribute__((ext_vector_type(8)));
typedef __bf16 bf16x4 __attribute__((ext_vector_type(4)));
typedef float  f32x4  __attribute__((ext_vector_type(4)));

static __device__ __forceinline__ f32x4 mfma16(bf16x8 a, bf16x8 b, f32x4 c) {
    return __builtin_amdgcn_mfma_f32_16x16x32_bf16(a, b, c, 0, 0, 0);
}

// DPP horizontal neighbors within 16-lane rows (= our pixel groups).
// row_shr:1 (0x111): lane i <- lane i-1 (left neighbor), row-edge lanes get 0.
// row_shl:1 (0x101): lane i <- lane i+1 (right neighbor).
static __device__ __forceinline__ float dpp_left(float v) {
    return __builtin_bit_cast(float, __builtin_amdgcn_update_dpp(
        0, __builtin_bit_cast(int, v), 0x111, 0xF, 0xF, true));
}
static __device__ __forceinline__ float dpp_right(float v) {
    return __builtin_bit_cast(float, __builtin_amdgcn_update_dpp(
        0, __builtin_bit_cast(int, v), 0x101, 0xF, 0xF, true));
}

// v9: wave-private restructure. Lane l of wave wv owns pixel 16*wv+(l&15),
// channels 4*(l>>4)..+3 -- the SAME (p,q) decomposition as the MFMA/epilogue.
//  - ZERO barriers in the main loop: sY rows 16wv..16wv+15 are written and
//    read only by wave wv (sH was already wave-private). Waves drift freely
//    across segments -> latency hiding via 12 independent waves/CU instead
//    of lockstep barrier convoys (v4's 2 barriers x 8 segments).
//  - loads/lane/segment 36 -> 12 (own column T/M/B x 4ch); horizontal
//    neighbors via DPP row_shr/row_shl (VALU, 16-lane rows); 12 extra
//    predicated loads on the 8 edge lanes only. Block loads 9216->3456/seg.
//  - sXC eliminated: epilogue xc[r] == this lane's fm[r] register (cg==q).
//  - NO register-pressure tricks (v5-v8 all ended in scratch or drops);
//    single T/M/B buffer, compiler-scheduled prefetch of segment s+1.
//  - keep: XCD row swizzle, packed b64 sY writes, sRU row in LDS, acc[8].
// LDS: 16+4+9+17+2 = 48 KB -> 3 blocks/CU.
__global__ __launch_bounds__(256, 3)
void ca_mfma9(const float* __restrict__ x, const float* __restrict__ w0,
              const float* __restrict__ b0, const float* __restrict__ w1,
              const float* __restrict__ ru, float* __restrict__ out)
{
    // frag-ordered weights: sW0[ks][t][lane][8], sW1[s][lane][8]
    __shared__ __align__(16) __bf16 sW0[2 * 8 * 64 * 8];   // 16 KB
    __shared__ __align__(16) __bf16 sW1[4 * 64 * 8];       //  4 KB
    __shared__ __align__(16) __bf16 sY[64 * YSTR];         //  9 KB
    __shared__ __align__(16) __bf16 sH[64 * HSTR];         // 17 KB
    __shared__ float sRU[WW];                              //  2 KB

    const int tid  = threadIdx.x;
    const int lane = tid & 63;
    const int wv   = tid >> 6;
    const int pxi  = lane & 15;   // pixel index within the wave's 16-px group
    const int cg   = lane >> 4;   // channel group (4 channels); == MFMA quad q
    const int q    = cg;

    // bijective XCD swizzle: XCD k owns rows [256k, 256k+256) -> halo rows
    // land in the same XCD's L2 (FETCH 113.7 -> ~36 MB measured)
    const int orig = blockIdx.x;
    const int row  = ((orig & 7) << 8) | (orig >> 3);
    const int b    = row >> 9;
    const int i    = row & (HH - 1);

    const size_t plane = (size_t)HH * WW;
    const float* xb    = x + (size_t)b * CH * plane + (size_t)i * WW;
    const bool   up    = (i > 0), dn = (i < HH - 1);
    const int    mypx  = 16 * wv + pxi;   // this lane's pixel (build AND mfma/epilogue)

    // own-column stencil: T/M/B per channel; e* = edge column for lanes
    // pxi==0 (global j-1) / pxi==15 (global j+1); others never read e*.
    float T[4], M[4], B[4];
    float eT[4] = {0,0,0,0}, eM[4] = {0,0,0,0}, eB[4] = {0,0,0,0};

    auto issue_loads = [&](int s) {
        const int j = s * 64 + mypx;
        #pragma unroll
        for (int k = 0; k < 4; ++k) {
            const float* c0 = xb + (size_t)(4 * cg + k) * plane + j;
            T[k] = up ? c0[-WW] : 0.f;
            M[k] =      c0[0];
            B[k] = dn ? c0[WW]  : 0.f;
        }
        if (pxi == 0 || pxi == 15) {
            const int jj = (pxi == 0) ? (j - 1) : (j + 1);
            const bool ok = (jj >= 0) && (jj < WW);
            #pragma unroll
            for (int k = 0; k < 4; ++k) {
                const float* c1 = xb + (size_t)(4 * cg + k) * plane + jj;
                eT[k] = (ok && up) ? c1[-WW] : 0.f;
                eM[k] =  ok        ? c1[0]   : 0.f;
                eB[k] = (ok && dn) ? c1[WW]  : 0.f;
            }
        }
    };

    // segment-0 loads fly under the weight staging + prologue barrier
    issue_loads(0);

    // ---- stage W0 (+bias at k==48) into LDS, frag-ordered ----
    for (int e = tid; e < 1024; e += 256) {
        const int ks = e >> 9, rem = e & 511;
        const int t = rem >> 6, ln = rem & 63;
        const int pp = ln & 15, qq = ln >> 4;
        const int o = 16 * t + pp;
        bf16x8 v;
        #pragma unroll
        for (int j = 0; j < 8; ++j) {
            const int k = 32 * ks + 8 * qq + j;
            float val;
            if (k < K3)       val = w0[o * K3 + k];
            else if (k == K3) val = b0[o];
            else              val = 0.f;
            v[j] = (__bf16)val;
        }
        *(bf16x8*)&sW0[e * 8] = v;
    }
    // ---- stage W1 [16 x 128] frag-ordered: one entry per thread ----
    {
        const int e = tid;
        const int s = e >> 6, ln = e & 63;
        const int pp = ln & 15, qq = ln >> 4;
        bf16x8 v;
        #pragma unroll
        for (int j = 0; j < 8; ++j)
            v[j] = (__bf16)w1[pp * HID + 32 * s + 8 * qq + j];
        *(bf16x8*)&sW1[e * 8] = v;
    }
    // ---- stage the mask row (512 floats) ----
    for (int e = tid; e < WW; e += 256)
        sRU[e] = ru[(size_t)b * plane + (size_t)i * WW + e];
    // ---- static K-pad of sY: feature 48 = 1.0 (bias), 49..63 = 0 ----
    if (tid < 64) {
        bf16x4 zb = {(__bf16)1.0f, (__bf16)0.f, (__bf16)0.f, (__bf16)0.f};
        bf16x4 zz = {(__bf16)0.f, (__bf16)0.f, (__bf16)0.f, (__bf16)0.f};
        *(bf16x4*)&sY[tid * YSTR + 48] = zb;
        *(bf16x4*)&sY[tid * YSTR + 52] = zz;
        *(bf16x4*)&sY[tid * YSTR + 56] = zz;
        *(bf16x4*)&sY[tid * YSTR + 60] = zz;
    }
    asm volatile("s_waitcnt lgkmcnt(0)");
    __builtin_amdgcn_s_barrier();   // the ONLY barrier in the kernel

    for (int s = 0; s < 8; ++s) {
        // ---- Sobel via DPP neighbors (consumes T/M/B/e*; VALU only) ----
        float fm[4], fgx[4], fgy[4];
        #pragma unroll
        for (int k = 0; k < 4; ++k) {
            float lT = dpp_left(T[k]),  lM = dpp_left(M[k]),  lB = dpp_left(B[k]);
            float rT = dpp_right(T[k]), rM = dpp_right(M[k]), rB = dpp_right(B[k]);
            if (pxi == 0)  { lT = eT[k]; lM = eM[k]; lB = eB[k]; }
            if (pxi == 15) { rT = eT[k]; rM = eM[k]; rB = eB[k]; }
            fm[k]  = M[k];
            fgx[k] = (rT - lT) + 2.f * (rM - lM) + (rB - lB);
            fgy[k] = (lB - lT) + 2.f * (B[k] - T[k]) + (rB - rT);
        }
        // ---- write this lane's features to its wave-private sY row ----
        {
            bf16x4 vm = {(__bf16)fm[0],  (__bf16)fm[1],  (__bf16)fm[2],  (__bf16)fm[3]};
            bf16x4 vx = {(__bf16)fgx[0], (__bf16)fgx[1], (__bf16)fgx[2], (__bf16)fgx[3]};
            bf16x4 vy = {(__bf16)fgy[0], (__bf16)fgy[1], (__bf16)fgy[2], (__bf16)fgy[3]};
            *(bf16x4*)&sY[mypx * YSTR + 4 * cg]          = vm;
            *(bf16x4*)&sY[mypx * YSTR + CH + 4 * cg]     = vx;
            *(bf16x4*)&sY[mypx * YSTR + 2 * CH + 4 * cg] = vy;
        }
        // T/M/B dead -> prefetch next segment (compiler-scheduled; flies
        // across the whole MFMA phase, no barrier to drain it)
        if (s < 7) issue_loads(s + 1);

        // ---- MFMA phase: same-wave sY write->read (compiler inserts the
        // lgkmcnt; this same-wave LDS discipline is proven by sH since v3) --
        const bf16x8 yb0 = *(const bf16x8*)&sY[mypx * YSTR + 8 * q];
        const bf16x8 yb1 = *(const bf16x8*)&sY[mypx * YSTR + 32 + 8 * q];

        f32x4 acc[8];
        #pragma unroll
        for (int t = 0; t < 8; ++t) {
            const bf16x8 a0 = *(const bf16x8*)&sW0[((0 * 8 + t) * 64 + lane) * 8];
            const bf16x8 a1 = *(const bf16x8*)&sW0[((1 * 8 + t) * 64 + lane) * 8];
            acc[t] = f32x4{0.f, 0.f, 0.f, 0.f};
            acc[t] = mfma16(a0, yb0, acc[t]);
            acc[t] = mfma16(a1, yb1, acc[t]);
        }
        // relu + cvt -> sH[mypx][o], o = 16t + 4q + r (wave-private rows)
        #pragma unroll
        for (int t = 0; t < 8; ++t) {
            bf16x4 hv;
            #pragma unroll
            for (int r = 0; r < 4; ++r)
                hv[r] = (__bf16)fmaxf(acc[t][r], 0.f);
            *(bf16x4*)&sH[mypx * HSTR + 16 * t + 4 * q] = hv;
        }
        // same-wave LDS write->read: no barrier
        f32x4 u = f32x4{0.f, 0.f, 0.f, 0.f};
        #pragma unroll
        for (int ss = 0; ss < 4; ++ss) {
            const bf16x8 hb = *(const bf16x8*)&sH[mypx * HSTR + 32 * ss + 8 * q];
            const bf16x8 aw = *(const bf16x8*)&sW1[(ss * 64 + lane) * 8];
            u = mfma16(aw, hb, u);
        }

        // ---- epilogue: out[c][jg] = fm[r] + u[r]*mask, c = 4q + r ----
        // (xc comes straight from this lane's fm registers: cg == q)
        const int jg = s * 64 + mypx;
        const float rv = sRU[jg];
        const float m  = (rv > 0.5f) ? 1.f : 0.f;
        float* ob = out + (size_t)b * CH * plane + (size_t)i * WW + jg;
        #pragma unroll
        for (int r = 0; r < 4; ++r) {
            const int c = 4 * q + r;
            ob[(size_t)c * plane] = fmaf(u[r], m, fm[r]);
        }
    }
}

extern "C" void kernel_launch(void* const* d_in, const int* in_sizes, int n_in,
                              void* d_out, int out_size, void* d_ws, size_t ws_size,
                              hipStream_t stream) {
    const float* x  = (const float*)d_in[0];
    const float* w0 = (const float*)d_in[1];
    const float* b0 = (const float*)d_in[2];
    const float* w1 = (const float*)d_in[3];
    const float* ru = (const float*)d_in[4];
    float* out = (float*)d_out;

    dim3 grid(BATCH * HH);   // 2048 blocks: one per (batch, image row)
    dim3 block(256);
    hipLaunchKernelGGL(ca_mfma9, grid, block, 0, stream, x, w0, b0, w1, ru, out);
}

// Round 7
// 192.276 us; speedup vs baseline: 1.3705x; 1.0016x over previous
//
#include <hip/hip_runtime.h>
#include <cstddef>

#define BATCH 4
#define CH    16
#define HH    512
#define WW    512
#define HID   128
#define K3    48      // 3*CH
#define YSTR  72      // sY row stride bf16 (64 feat slots + 8 pad); 144 B, b128-aligned reads
#define HSTR  136     // sH row stride (128 + 8 bank-pad), 272 B

typedef __bf16 bf16x8 __attribute__((ext_vector_type(8)));
typedef __bf16 bf16x4 __attribute__((ext_vector_type(4)));
typedef float  f32x4  __attribute__((ext_vector_type(4)));

static __device__ __forceinline__ f32x4 mfma16(bf16x8 a, bf16x8 b, f32x4 c) {
    return __builtin_amdgcn_mfma_f32_16x16x32_bf16(a, b, c, 0, 0, 0);
}

// DPP horizontal neighbors within 16-lane rows (= our pixel groups).
static __device__ __forceinline__ float dpp_left(float v) {
    return __builtin_bit_cast(float, __builtin_amdgcn_update_dpp(
        0, __builtin_bit_cast(int, v), 0x111, 0xF, 0xF, true));
}
static __device__ __forceinline__ float dpp_right(float v) {
    return __builtin_bit_cast(float, __builtin_amdgcn_update_dpp(
        0, __builtin_bit_cast(int, v), 0x101, 0xF, 0xF, true));
}

// v10 = v9 (wave-private, barrier-free, DPP stencil; 97us measured) +
// register-resident W0 fragments. Why this pin can finally succeed:
// v6/v8 pins failed on structures whose peak pressure REALLY exceeded the
// 168-VGPR cap (3 waves/EU): v6 ~230 (LA+LB+acc32+frags), v8 ~180 (LA+LB).
// v9 is slim (VGPR=80, no LA/LB). Pin = 64 VGPR; to stay under the cap the
// MFMA phase is split into two half-batches of 4 t's (acc live 32->16,
// ILP=4 chains -- NOT v7's per-t ILP=1 which tanked MfmaUtil).
// Peak live ~ TMB(12)+edge(12)+fm(4)+yb(16)+acc(16)+pin(64)+misc(20) ~ 144.
// Removes 16 ds_read_b128 per wave-segment (~190 of ~400 LDS-pipe cycles,
// the hottest pipe at ~50% busy).
// GATES: WRITE_SIZE must stay ~66 MB (spill -> revert); VGPR ~135-160.
__global__ __launch_bounds__(256, 3)
void ca_mfma10(const float* __restrict__ x, const float* __restrict__ w0,
               const float* __restrict__ b0, const float* __restrict__ w1,
               const float* __restrict__ ru, float* __restrict__ out)
{
    // frag-ordered weights: sW0[ks][t][lane][8], sW1[s][lane][8]
    __shared__ __align__(16) __bf16 sW0[2 * 8 * 64 * 8];   // 16 KB (prologue only)
    __shared__ __align__(16) __bf16 sW1[4 * 64 * 8];       //  4 KB
    __shared__ __align__(16) __bf16 sY[64 * YSTR];         //  9 KB
    __shared__ __align__(16) __bf16 sH[64 * HSTR];         // 17 KB
    __shared__ float sRU[WW];                              //  2 KB (48 KB total, 3 blk/CU)

    const int tid  = threadIdx.x;
    const int lane = tid & 63;
    const int wv   = tid >> 6;
    const int pxi  = lane & 15;   // pixel index within the wave's 16-px group
    const int cg   = lane >> 4;   // channel group (4 channels); == MFMA quad q
    const int q    = cg;

    // bijective XCD swizzle: XCD k owns rows [256k, 256k+256)
    const int orig = blockIdx.x;
    const int row  = ((orig & 7) << 8) | (orig >> 3);
    const int b    = row >> 9;
    const int i    = row & (HH - 1);

    const size_t plane = (size_t)HH * WW;
    const float* xb    = x + (size_t)b * CH * plane + (size_t)i * WW;
    const bool   up    = (i > 0), dn = (i < HH - 1);
    const int    mypx  = 16 * wv + pxi;

    // own-column stencil: T/M/B per channel; e* = edge column for lanes
    // pxi==0 (global j-1) / pxi==15 (global j+1)
    float T[4], M[4], B[4];
    float eT[4] = {0,0,0,0}, eM[4] = {0,0,0,0}, eB[4] = {0,0,0,0};

    auto issue_loads = [&](int s) {
        const int j = s * 64 + mypx;
        #pragma unroll
        for (int k = 0; k < 4; ++k) {
            const float* c0 = xb + (size_t)(4 * cg + k) * plane + j;
            T[k] = up ? c0[-WW] : 0.f;
            M[k] =      c0[0];
            B[k] = dn ? c0[WW]  : 0.f;
        }
        if (pxi == 0 || pxi == 15) {
            const int jj = (pxi == 0) ? (j - 1) : (j + 1);
            const bool ok = (jj >= 0) && (jj < WW);
            #pragma unroll
            for (int k = 0; k < 4; ++k) {
                const float* c1 = xb + (size_t)(4 * cg + k) * plane + jj;
                eT[k] = (ok && up) ? c1[-WW] : 0.f;
                eM[k] =  ok        ? c1[0]   : 0.f;
                eB[k] = (ok && dn) ? c1[WW]  : 0.f;
            }
        }
    };

    issue_loads(0);

    // ---- stage W0 (+bias at k==48) into LDS, frag-ordered ----
    for (int e = tid; e < 1024; e += 256) {
        const int ks = e >> 9, rem = e & 511;
        const int t = rem >> 6, ln = rem & 63;
        const int pp = ln & 15, qq = ln >> 4;
        const int o = 16 * t + pp;
        bf16x8 v;
        #pragma unroll
        for (int j = 0; j < 8; ++j) {
            const int k = 32 * ks + 8 * qq + j;
            float val;
            if (k < K3)       val = w0[o * K3 + k];
            else if (k == K3) val = b0[o];
            else              val = 0.f;
            v[j] = (__bf16)val;
        }
        *(bf16x8*)&sW0[e * 8] = v;
    }
    // ---- stage W1 [16 x 128] frag-ordered ----
    {
        const int e = tid;
        const int s = e >> 6, ln = e & 63;
        const int pp = ln & 15, qq = ln >> 4;
        bf16x8 v;
        #pragma unroll
        for (int j = 0; j < 8; ++j)
            v[j] = (__bf16)w1[pp * HID + 32 * s + 8 * qq + j];
        *(bf16x8*)&sW1[e * 8] = v;
    }
    // ---- stage the mask row ----
    for (int e = tid; e < WW; e += 256)
        sRU[e] = ru[(size_t)b * plane + (size_t)i * WW + e];
    // ---- static K-pad of sY: feature 48 = 1.0 (bias), 49..63 = 0 ----
    if (tid < 64) {
        bf16x4 zb = {(__bf16)1.0f, (__bf16)0.f, (__bf16)0.f, (__bf16)0.f};
        bf16x4 zz = {(__bf16)0.f, (__bf16)0.f, (__bf16)0.f, (__bf16)0.f};
        *(bf16x4*)&sY[tid * YSTR + 48] = zb;
        *(bf16x4*)&sY[tid * YSTR + 52] = zz;
        *(bf16x4*)&sY[tid * YSTR + 56] = zz;
        *(bf16x4*)&sY[tid * YSTR + 60] = zz;
    }
    asm volatile("s_waitcnt lgkmcnt(0)");
    __builtin_amdgcn_s_barrier();   // the only barrier in the kernel

    // ---- pin all 16 W0 fragments in 64 VGPRs. "+v" asm makes each value
    // asm-defined (un-rematerializable): RA must keep it live. v9's slim
    // structure leaves headroom (~80 + 64 + temps ~ 144 < 168 cap). ----
    bf16x8 a0r[8], a1r[8];
    #pragma unroll
    for (int t = 0; t < 8; ++t) {
        a0r[t] = *(const bf16x8*)&sW0[((0 * 8 + t) * 64 + lane) * 8];
        a1r[t] = *(const bf16x8*)&sW0[((1 * 8 + t) * 64 + lane) * 8];
        asm volatile("" : "+v"(a0r[t]));
        asm volatile("" : "+v"(a1r[t]));
    }

    for (int s = 0; s < 8; ++s) {
        // ---- Sobel via DPP neighbors ----
        float fm[4], fgx[4], fgy[4];
        #pragma unroll
        for (int k = 0; k < 4; ++k) {
            float lT = dpp_left(T[k]),  lM = dpp_left(M[k]),  lB = dpp_left(B[k]);
            float rT = dpp_right(T[k]), rM = dpp_right(M[k]), rB = dpp_right(B[k]);
            if (pxi == 0)  { lT = eT[k]; lM = eM[k]; lB = eB[k]; }
            if (pxi == 15) { rT = eT[k]; rM = eM[k]; rB = eB[k]; }
            fm[k]  = M[k];
            fgx[k] = (rT - lT) + 2.f * (rM - lM) + (rB - lB);
            fgy[k] = (lB - lT) + 2.f * (B[k] - T[k]) + (rB - rT);
        }
        // ---- write features to the wave-private sY row ----
        {
            bf16x4 vm = {(__bf16)fm[0],  (__bf16)fm[1],  (__bf16)fm[2],  (__bf16)fm[3]};
            bf16x4 vx = {(__bf16)fgx[0], (__bf16)fgx[1], (__bf16)fgx[2], (__bf16)fgx[3]};
            bf16x4 vy = {(__bf16)fgy[0], (__bf16)fgy[1], (__bf16)fgy[2], (__bf16)fgy[3]};
            *(bf16x4*)&sY[mypx * YSTR + 4 * cg]          = vm;
            *(bf16x4*)&sY[mypx * YSTR + CH + 4 * cg]     = vx;
            *(bf16x4*)&sY[mypx * YSTR + 2 * CH + 4 * cg] = vy;
        }
        // T/M/B dead -> prefetch next segment (compiler-scheduled)
        if (s < 7) issue_loads(s + 1);

        // ---- MFMA phase (same-wave sY write->read) ----
        const bf16x8 yb0 = *(const bf16x8*)&sY[mypx * YSTR + 8 * q];
        const bf16x8 yb1 = *(const bf16x8*)&sY[mypx * YSTR + 32 + 8 * q];

        // two half-batches of 4 t's: acc live 16 regs, ILP=4 chains
        #pragma unroll
        for (int h = 0; h < 2; ++h) {
            f32x4 acc[4];
            #pragma unroll
            for (int tt = 0; tt < 4; ++tt) {
                const int t = 4 * h + tt;
                acc[tt] = f32x4{0.f, 0.f, 0.f, 0.f};
                acc[tt] = mfma16(a0r[t], yb0, acc[tt]);
                acc[tt] = mfma16(a1r[t], yb1, acc[tt]);
            }
            #pragma unroll
            for (int tt = 0; tt < 4; ++tt) {
                const int t = 4 * h + tt;
                bf16x4 hv;
                #pragma unroll
                for (int r = 0; r < 4; ++r)
                    hv[r] = (__bf16)fmaxf(acc[tt][r], 0.f);
                *(bf16x4*)&sH[mypx * HSTR + 16 * t + 4 * q] = hv;
            }
        }
        // same-wave LDS write->read: no barrier
        f32x4 u = f32x4{0.f, 0.f, 0.f, 0.f};
        #pragma unroll
        for (int ss = 0; ss < 4; ++ss) {
            const bf16x8 hb = *(const bf16x8*)&sH[mypx * HSTR + 32 * ss + 8 * q];
            const bf16x8 aw = *(const bf16x8*)&sW1[(ss * 64 + lane) * 8];
            u = mfma16(aw, hb, u);
        }

        // ---- epilogue: out[c][jg] = fm[r] + u[r]*mask, c = 4q + r ----
        const int jg = s * 64 + mypx;
        const float rv = sRU[jg];
        const float m  = (rv > 0.5f) ? 1.f : 0.f;
        float* ob = out + (size_t)b * CH * plane + (size_t)i * WW + jg;
        #pragma unroll
        for (int r = 0; r < 4; ++r) {
            const int c = 4 * q + r;
            ob[(size_t)c * plane] = fmaf(u[r], m, fm[r]);
        }
    }
}

extern "C" void kernel_launch(void* const* d_in, const int* in_sizes, int n_in,
                              void* d_out, int out_size, void* d_ws, size_t ws_size,
                              hipStream_t stream) {
    const float* x  = (const float*)d_in[0];
    const float* w0 = (const float*)d_in[1];
    const float* b0 = (const float*)d_in[2];
    const float* w1 = (const float*)d_in[3];
    const float* ru = (const float*)d_in[4];
    float* out = (float*)d_out;

    dim3 grid(BATCH * HH);   // 2048 blocks: one per (batch, image row)
    dim3 block(256);
    hipLaunchKernelGGL(ca_mfma10, grid, block, 0, stream, x, w0, b0, w1, ru, out);
}